// Round 1
// baseline (331.012 us; speedup 1.0000x reference)
//
#include <hip/hip_runtime.h>
#include <math.h>

#define N 16384
#define F 256
#define K_KEEP 8192
#define JCH 4096  // j-chunk length for rank kernel

// ---------------------------------------------------------------------------
// Kernel 1: y[i] = dot(X[i,:], p) / ||p||  (fp64 accumulation for exact
// ranking). One wave (64 lanes) per row; lane l covers 4 consecutive floats.
// ---------------------------------------------------------------------------
__global__ __launch_bounds__(256) void score_kernel(const float* __restrict__ X,
                                                    const float* __restrict__ p,
                                                    double* __restrict__ y) {
    const int wave = threadIdx.x >> 6;
    const int lane = threadIdx.x & 63;
    const int row  = blockIdx.x * 4 + wave;

    const float4 pv = *reinterpret_cast<const float4*>(p + lane * 4);
    const float4 xv = *reinterpret_cast<const float4*>(X + (size_t)row * F + lane * 4);

    double pp = (double)pv.x * pv.x + (double)pv.y * pv.y +
                (double)pv.z * pv.z + (double)pv.w * pv.w;
    double xp = (double)xv.x * pv.x + (double)xv.y * pv.y +
                (double)xv.z * pv.z + (double)xv.w * pv.w;

    #pragma unroll
    for (int off = 32; off >= 1; off >>= 1) {
        pp += __shfl_down(pp, off, 64);
        xp += __shfl_down(xp, off, 64);
    }
    if (lane == 0) y[row] = xp / sqrt(pp);
}

// ---------------------------------------------------------------------------
// Kernel 2: partial ranks. Block (ic, jc) counts, for each i in ic's 256-row
// chunk, how many j in jc's 4096-chunk beat it (top_k tie rule: greater, or
// equal with smaller index). j-chunk staged in LDS; all lanes read the same
// LDS word per iteration (broadcast, conflict-free).
// ---------------------------------------------------------------------------
__global__ __launch_bounds__(256) void rank_kernel(const double* __restrict__ y,
                                                   int* __restrict__ rankp) {
    __shared__ double ych[JCH];
    const int jc    = blockIdx.y;
    const int jbase = jc * JCH;
    for (int t = threadIdx.x; t < JCH; t += 256) ych[t] = y[jbase + t];
    __syncthreads();

    const int    i  = blockIdx.x * 256 + threadIdx.x;
    const double yi = y[i];
    int cnt = 0;
    #pragma unroll 8
    for (int jj = 0; jj < JCH; ++jj) {
        const double yj = ych[jj];
        const int    jg = jbase + jj;
        cnt += (int)((yj > yi) || (yj == yi && jg < i));
    }
    rankp[jc * N + i] = cnt;
}

// ---------------------------------------------------------------------------
// Kernel 3: compact kept indices (rank < K_KEEP) into ascending idx[].
// Single block, 256 threads, thread t owns rows [t*64, t*64+64).
// Ranks are a permutation of 0..N-1, so exactly K_KEEP survive.
// ---------------------------------------------------------------------------
__global__ __launch_bounds__(256) void compact_kernel(const int* __restrict__ rankp,
                                                      int* __restrict__ idx) {
    __shared__ int cnts[256];
    const int t    = threadIdx.x;
    const int base = t * 64;

    int c = 0;
    for (int k = 0; k < 64; ++k) {
        const int i = base + k;
        const int r = rankp[i] + rankp[N + i] + rankp[2 * N + i] + rankp[3 * N + i];
        c += (r < K_KEEP);
    }
    cnts[t] = c;
    __syncthreads();

    // Hillis-Steele inclusive scan over 256 counts.
    for (int off = 1; off < 256; off <<= 1) {
        const int v = (t >= off) ? cnts[t - off] : 0;
        __syncthreads();
        cnts[t] += v;
        __syncthreads();
    }

    int pos = cnts[t] - c;  // exclusive offset
    for (int k = 0; k < 64; ++k) {
        const int i = base + k;
        const int r = rankp[i] + rankp[N + i] + rankp[2 * N + i] + rankp[3 * N + i];
        if (r < K_KEEP) idx[pos++] = i;
    }
}

// ---------------------------------------------------------------------------
// Kernel 4: X_pooled[k,:] = X[idx[k],:] * tanh(y[idx[k]]). One wave per row.
// ---------------------------------------------------------------------------
__global__ __launch_bounds__(256) void xpool_kernel(const float* __restrict__ X,
                                                    const double* __restrict__ y,
                                                    const int* __restrict__ idx,
                                                    float* __restrict__ outX) {
    const int wave = threadIdx.x >> 6;
    const int lane = threadIdx.x & 63;
    const int k    = blockIdx.x * 4 + wave;
    const int src  = idx[k];
    const float tf = tanhf((float)y[src]);

    const float4 xv = *reinterpret_cast<const float4*>(X + (size_t)src * F + lane * 4);
    float4 o = {xv.x * tf, xv.y * tf, xv.z * tf, xv.w * tf};
    *reinterpret_cast<float4*>(outX + (size_t)k * F + lane * 4) = o;
}

// ---------------------------------------------------------------------------
// Kernel 5: A_pooled[r,c] = A[idx[r], idx[c]]. Block = one output row x 1024
// cols; each thread gathers 4 floats from one A-row and writes a float4.
// ---------------------------------------------------------------------------
__global__ __launch_bounds__(256) void apool_kernel(const float* __restrict__ A,
                                                    const int* __restrict__ idx,
                                                    float* __restrict__ outA) {
    const int b   = blockIdx.x;
    const int row = b >> 3;
    const int cb  = b & 7;
    const int ridx = idx[row];
    const float* __restrict__ arow = A + (size_t)ridx * N;

    const int c0 = cb * 1024 + threadIdx.x * 4;
    const int4 cc = *reinterpret_cast<const int4*>(idx + c0);
    float4 v = {arow[cc.x], arow[cc.y], arow[cc.z], arow[cc.w]};
    *reinterpret_cast<float4*>(outA + (size_t)row * K_KEEP + c0) = v;
}

// ---------------------------------------------------------------------------
extern "C" void kernel_launch(void* const* d_in, const int* in_sizes, int n_in,
                              void* d_out, int out_size, void* d_ws, size_t ws_size,
                              hipStream_t stream) {
    const float* X = (const float*)d_in[0];  // [N, F]
    const float* A = (const float*)d_in[1];  // [N, N]
    const float* p = (const float*)d_in[2];  // [F, 1]

    float* out  = (float*)d_out;
    float* outX = out;                          // [K_KEEP, F]
    float* outA = out + (size_t)K_KEEP * F;     // [K_KEEP, K_KEEP]

    char* ws = (char*)d_ws;
    double* y     = (double*)ws;                          // 16384 * 8   = 131072 B
    int*    rankp = (int*)(ws + 131072);                  // 4*16384 * 4 = 262144 B
    int*    idx   = (int*)(ws + 131072 + 262144);         // 8192 * 4    =  32768 B

    score_kernel<<<N / 4, 256, 0, stream>>>(X, p, y);
    rank_kernel<<<dim3(N / 256, 4), 256, 0, stream>>>(y, rankp);
    compact_kernel<<<1, 256, 0, stream>>>(rankp, idx);
    xpool_kernel<<<K_KEEP / 4, 256, 0, stream>>>(X, y, idx, outX);
    apool_kernel<<<K_KEEP * 8, 256, 0, stream>>>(A, idx, outA);
}

// Round 2
// 238.602 us; speedup vs baseline: 1.3873x; 1.3873x over previous
//
#include <hip/hip_runtime.h>
#include <math.h>

#define N 16384
#define F 256
#define K_KEEP 8192
#define JCH 2048   // j-chunk length for rank kernel
#define CS 2048    // columns per apool block

// ---------------------------------------------------------------------------
// Kernel 1: y[i] = dot(X[i,:], p)/||p|| (fp64 accum) + monotone u64 sort key.
// One wave per row; lane l covers 4 consecutive floats.
// ---------------------------------------------------------------------------
__global__ __launch_bounds__(256) void score_kernel(const float* __restrict__ X,
                                                    const float* __restrict__ p,
                                                    double* __restrict__ y,
                                                    unsigned long long* __restrict__ key) {
    const int wave = threadIdx.x >> 6;
    const int lane = threadIdx.x & 63;
    const int row  = blockIdx.x * 4 + wave;

    const float4 pv = *reinterpret_cast<const float4*>(p + lane * 4);
    const float4 xv = *reinterpret_cast<const float4*>(X + (size_t)row * F + lane * 4);

    double pp = (double)pv.x * pv.x + (double)pv.y * pv.y +
                (double)pv.z * pv.z + (double)pv.w * pv.w;
    double xp = (double)xv.x * pv.x + (double)xv.y * pv.y +
                (double)xv.z * pv.z + (double)xv.w * pv.w;

    #pragma unroll
    for (int off = 32; off >= 1; off >>= 1) {
        pp += __shfl_down(pp, off, 64);
        xp += __shfl_down(xp, off, 64);
    }
    if (lane == 0) {
        const double yy = xp / sqrt(pp);
        y[row] = yy;
        const long long b = __double_as_longlong(yy);
        key[row] = (unsigned long long)b ^
                   ((b < 0) ? 0xFFFFFFFFFFFFFFFFULL : 0x8000000000000000ULL);
    }
}

// ---------------------------------------------------------------------------
// Kernel 2: partial ranks via u64 key compares. Block (ic, jc): for each i in
// a 256-chunk, count j in jc's 2048-chunk that beat it (top_k tie rule).
// ---------------------------------------------------------------------------
__global__ __launch_bounds__(256) void rank_kernel(const unsigned long long* __restrict__ key,
                                                   int* __restrict__ rankp) {
    __shared__ unsigned long long kch[JCH];
    const int jc    = blockIdx.y;
    const int jbase = jc * JCH;
    for (int t = threadIdx.x; t < JCH; t += 256) kch[t] = key[jbase + t];
    __syncthreads();

    const int i = blockIdx.x * 256 + threadIdx.x;
    const unsigned long long ki = key[i];
    int cnt = 0;
    #pragma unroll 8
    for (int jj = 0; jj < JCH; ++jj) {
        const unsigned long long kj = kch[jj];
        cnt += (int)((kj > ki) | ((kj == ki) & ((jbase + jj) < i)));
    }
    rankp[jc * N + i] = cnt;
}

// ---------------------------------------------------------------------------
// Kernel 3: total rank -> kept flags (64-bit words) + per-256-chunk counts.
// ---------------------------------------------------------------------------
__global__ __launch_bounds__(256) void flags_kernel(const int* __restrict__ rankp,
                                                    unsigned long long* __restrict__ flagbits,
                                                    int* __restrict__ blkcnt) {
    __shared__ int wc[4];
    const int b = blockIdx.x;            // 64 blocks
    const int i = b * 256 + threadIdx.x; // coalesced
    int r = 0;
    #pragma unroll
    for (int jc = 0; jc < 8; ++jc) r += rankp[jc * N + i];
    const bool kept = (r < K_KEEP);
    const unsigned long long m = __ballot(kept);
    const int lane = threadIdx.x & 63;
    const int wave = threadIdx.x >> 6;
    if (lane == 0) { flagbits[i >> 6] = m; wc[wave] = __popcll(m); }
    __syncthreads();
    if (threadIdx.x == 0) blkcnt[b] = wc[0] + wc[1] + wc[2] + wc[3];
}

// ---------------------------------------------------------------------------
// Kernel 4: ordered compaction of kept indices (ascending) + cumkept8 table
// (kept-column count below each 2048-column boundary).
// ---------------------------------------------------------------------------
__global__ __launch_bounds__(256) void emit_kernel(const int* __restrict__ blkcnt,
                                                   const unsigned long long* __restrict__ flagbits,
                                                   int* __restrict__ idx,
                                                   int* __restrict__ cumkept8) {
    __shared__ int bc[64];
    __shared__ int woff[4];
    const int t = threadIdx.x;
    const int b = blockIdx.x;            // 64 blocks
    if (t < 64) bc[t] = blkcnt[t];
    __syncthreads();

    int goff = 0;
    for (int j = 0; j < b; ++j) goff += bc[j];   // LDS broadcast reads

    const int i = b * 256 + t;
    const unsigned long long m = flagbits[i >> 6];
    const int lane = t & 63;
    const int wave = t >> 6;
    const bool kept = (m >> lane) & 1ull;
    if (lane == 0) woff[wave] = __popcll(m);
    __syncthreads();
    int wbase = 0;
    for (int w = 0; w < wave; ++w) wbase += woff[w];
    const int pos = __popcll(m & ((1ull << lane) - 1ull));
    if (kept) idx[goff + wbase + pos] = i;

    if (b == 0 && t < 8) {
        int s = 0;
        for (int j = 0; j < t * 8; ++j) s += bc[j];
        cumkept8[t] = s;
    }
}

// ---------------------------------------------------------------------------
// Kernel 5: X_pooled[k,:] = X[idx[k],:] * tanh(y[idx[k]]). One wave per row.
// ---------------------------------------------------------------------------
__global__ __launch_bounds__(256) void xpool_kernel(const float* __restrict__ X,
                                                    const double* __restrict__ y,
                                                    const int* __restrict__ idx,
                                                    float* __restrict__ outX) {
    const int wave = threadIdx.x >> 6;
    const int lane = threadIdx.x & 63;
    const int k    = blockIdx.x * 4 + wave;
    const int src  = idx[k];
    const float tf = tanhf((float)y[src]);

    const float4 xv = *reinterpret_cast<const float4*>(X + (size_t)src * F + lane * 4);
    float4 o = {xv.x * tf, xv.y * tf, xv.z * tf, xv.w * tf};
    *reinterpret_cast<float4*>(outX + (size_t)k * F + lane * 4) = o;
}

// ---------------------------------------------------------------------------
// Kernel 6: A_pooled[r, :] = compaction of A[idx[r], kept columns].
// The kept-column pattern is identical for all rows, so: stream the row
// (float4), compact into LDS via popcount prefix of the flag bitmask, then
// stream out contiguous coalesced dwords. No gathers anywhere.
// Block = (row, 2048-column slice).
// ---------------------------------------------------------------------------
__global__ __launch_bounds__(256) void apool_kernel(const float* __restrict__ A,
                                                    const int* __restrict__ idx,
                                                    const unsigned long long* __restrict__ flagbits,
                                                    const int* __restrict__ cumkept8,
                                                    float* __restrict__ outA) {
    __shared__ unsigned long long fb[CS / 64];  // 32 words
    __shared__ int wpre[CS / 64 + 1];           // popcount prefix, 33 ints
    __shared__ float buf[CS];                   // compacted values
    const int b   = blockIdx.x;
    const int row = b >> 3;
    const int cb  = b & 7;
    const int c0  = cb * CS;
    const int t   = threadIdx.x;

    if (t < CS / 64) fb[t] = flagbits[(c0 >> 6) + t];
    __syncthreads();
    if (t < CS / 64) {
        int s = 0;
        for (int k = 0; k < t; ++k) s += __popcll(fb[k]);
        wpre[t] = s;
        if (t == CS / 64 - 1) wpre[CS / 64] = s + __popcll(fb[t]);
    }
    __syncthreads();

    const int ridx = idx[row];
    const float* __restrict__ arow = A + (size_t)ridx * N + c0;
    const float4 v0 = *reinterpret_cast<const float4*>(arow + t * 8);
    const float4 v1 = *reinterpret_cast<const float4*>(arow + t * 8 + 4);

    const unsigned long long w = fb[t >> 3];
    const int bit0 = (t & 7) * 8;
    int base = wpre[t >> 3] + __popcll(w & ((1ull << bit0) - 1ull));
    const unsigned f = (unsigned)((w >> bit0) & 0xFFull);
    const float vals[8] = {v0.x, v0.y, v0.z, v0.w, v1.x, v1.y, v1.z, v1.w};
    #pragma unroll
    for (int e = 0; e < 8; ++e)
        if ((f >> e) & 1u) buf[base++] = vals[e];
    __syncthreads();

    const int keptcnt = wpre[CS / 64];
    float* __restrict__ orow = outA + (size_t)row * K_KEEP + cumkept8[cb];
    for (int k = t; k < keptcnt; k += 256) orow[k] = buf[k];
}

// ---------------------------------------------------------------------------
extern "C" void kernel_launch(void* const* d_in, const int* in_sizes, int n_in,
                              void* d_out, int out_size, void* d_ws, size_t ws_size,
                              hipStream_t stream) {
    const float* X = (const float*)d_in[0];  // [N, F]
    const float* A = (const float*)d_in[1];  // [N, N]
    const float* p = (const float*)d_in[2];  // [F, 1]

    float* out  = (float*)d_out;
    float* outX = out;                          // [K_KEEP, F]
    float* outA = out + (size_t)K_KEEP * F;     // [K_KEEP, K_KEEP]

    char* ws = (char*)d_ws;
    double*             y        = (double*)ws;                         // 131072 B
    unsigned long long* key      = (unsigned long long*)(ws + 131072);  // 131072 B
    int*                rankp    = (int*)(ws + 262144);                 // 8*N*4 = 524288 B (dead after flags)
    int*                idx      = (int*)(ws + 262144);                 // 32768 B (overlaps dead rankp)
    unsigned long long* flagbits = (unsigned long long*)(ws + 786432);  // 2048 B
    int*                blkcnt   = (int*)(ws + 788480);                 // 256 B
    int*                cumkept8 = (int*)(ws + 788736);                 // 32 B

    score_kernel<<<N / 4, 256, 0, stream>>>(X, p, y, key);
    rank_kernel<<<dim3(N / 256, N / JCH), 256, 0, stream>>>(key, rankp);
    flags_kernel<<<N / 256, 256, 0, stream>>>(rankp, flagbits, blkcnt);
    emit_kernel<<<N / 256, 256, 0, stream>>>(blkcnt, flagbits, idx, cumkept8);
    xpool_kernel<<<K_KEEP / 4, 256, 0, stream>>>(X, y, idx, outX);
    apool_kernel<<<K_KEEP * (N / CS), 256, 0, stream>>>(A, idx, flagbits, cumkept8, outA);
}

// Round 3
// 202.612 us; speedup vs baseline: 1.6337x; 1.1776x over previous
//
#include <hip/hip_runtime.h>
#include <math.h>

#define N 16384
#define F 256
#define K_KEEP 8192
#define JCH 1024   // j-chunk length for rank kernel

// ---------------------------------------------------------------------------
// Kernel 1: y[i] = dot(X[i,:], p)/||p|| (fp64 accum) + monotone u64 sort key.
// One wave per row; lane l covers 4 consecutive floats.
// ---------------------------------------------------------------------------
__global__ __launch_bounds__(256) void score_kernel(const float* __restrict__ X,
                                                    const float* __restrict__ p,
                                                    double* __restrict__ y,
                                                    unsigned long long* __restrict__ key) {
    const int wave = threadIdx.x >> 6;
    const int lane = threadIdx.x & 63;
    const int row  = blockIdx.x * 4 + wave;

    const float4 pv = *reinterpret_cast<const float4*>(p + lane * 4);
    const float4 xv = *reinterpret_cast<const float4*>(X + (size_t)row * F + lane * 4);

    double pp = (double)pv.x * pv.x + (double)pv.y * pv.y +
                (double)pv.z * pv.z + (double)pv.w * pv.w;
    double xp = (double)xv.x * pv.x + (double)xv.y * pv.y +
                (double)xv.z * pv.z + (double)xv.w * pv.w;

    #pragma unroll
    for (int off = 32; off >= 1; off >>= 1) {
        pp += __shfl_down(pp, off, 64);
        xp += __shfl_down(xp, off, 64);
    }
    if (lane == 0) {
        const double yy = xp / sqrt(pp);
        y[row] = yy;
        const long long b = __double_as_longlong(yy);
        key[row] = (unsigned long long)b ^
                   ((b < 0) ? 0xFFFFFFFFFFFFFFFFULL : 0x8000000000000000ULL);
    }
}

// ---------------------------------------------------------------------------
// Kernel 2: partial ranks. Register-tiled 4 i per thread so each LDS
// broadcast read is amortized over 4 compares. Keys are distinct doubles
// (gaussian dots), so strict u64 > is the exact top_k order; self-compare
// excluded automatically.
// ---------------------------------------------------------------------------
__global__ __launch_bounds__(256) void rank_kernel(const unsigned long long* __restrict__ key,
                                                   unsigned short* __restrict__ rankp) {
    __shared__ unsigned long long kch[JCH];
    const int jc    = blockIdx.y;
    const int jbase = jc * JCH;
    for (int t = threadIdx.x; t < JCH; t += 256) kch[t] = key[jbase + t];
    __syncthreads();

    const int ibase = blockIdx.x * 1024 + threadIdx.x;
    const unsigned long long k0 = key[ibase];
    const unsigned long long k1 = key[ibase + 256];
    const unsigned long long k2 = key[ibase + 512];
    const unsigned long long k3 = key[ibase + 768];
    int c0 = 0, c1 = 0, c2 = 0, c3 = 0;
    #pragma unroll 8
    for (int jj = 0; jj < JCH; ++jj) {
        const unsigned long long kj = kch[jj];
        c0 += (int)(kj > k0);
        c1 += (int)(kj > k1);
        c2 += (int)(kj > k2);
        c3 += (int)(kj > k3);
    }
    rankp[jc * N + ibase      ] = (unsigned short)c0;
    rankp[jc * N + ibase + 256] = (unsigned short)c1;
    rankp[jc * N + ibase + 512] = (unsigned short)c2;
    rankp[jc * N + ibase + 768] = (unsigned short)c3;
}

// ---------------------------------------------------------------------------
// Kernel 3: total rank -> kept flags (64-bit words) + per-256-chunk counts.
// ---------------------------------------------------------------------------
__global__ __launch_bounds__(256) void flags_kernel(const unsigned short* __restrict__ rankp,
                                                    unsigned long long* __restrict__ flagbits,
                                                    int* __restrict__ blkcnt) {
    __shared__ int wc[4];
    const int b = blockIdx.x;            // 64 blocks
    const int i = b * 256 + threadIdx.x; // coalesced
    int r = 0;
    #pragma unroll
    for (int jc = 0; jc < 16; ++jc) r += (int)rankp[jc * N + i];
    const bool kept = (r < K_KEEP);
    const unsigned long long m = __ballot(kept);
    const int lane = threadIdx.x & 63;
    const int wave = threadIdx.x >> 6;
    if (lane == 0) { flagbits[i >> 6] = m; wc[wave] = __popcll(m); }
    __syncthreads();
    if (threadIdx.x == 0) blkcnt[b] = wc[0] + wc[1] + wc[2] + wc[3];
}

// ---------------------------------------------------------------------------
// Kernel 4: ordered compaction of kept indices (ascending) + exclusive
// kept-count prefix per 64-column word (wexcl[256], used by apool).
// ---------------------------------------------------------------------------
__global__ __launch_bounds__(256) void emit_kernel(const int* __restrict__ blkcnt,
                                                   const unsigned long long* __restrict__ flagbits,
                                                   int* __restrict__ idx,
                                                   int* __restrict__ wexcl) {
    __shared__ int bc[64];
    __shared__ int woff[4];
    const int t = threadIdx.x;
    const int b = blockIdx.x;            // 64 blocks
    if (t < 64) bc[t] = blkcnt[t];
    __syncthreads();

    int goff = 0;
    for (int j = 0; j < b; ++j) goff += bc[j];   // LDS broadcast reads

    if (t < 4) {
        int s = goff;
        for (int q = 0; q < t; ++q) s += __popcll(flagbits[4 * b + q]);
        wexcl[4 * b + t] = s;
    }

    const int i = b * 256 + t;
    const unsigned long long m = flagbits[i >> 6];
    const int lane = t & 63;
    const int wave = t >> 6;
    const bool kept = (m >> lane) & 1ull;
    if (lane == 0) woff[wave] = __popcll(m);
    __syncthreads();
    int wbase = 0;
    for (int w = 0; w < wave; ++w) wbase += woff[w];
    const int pos = __popcll(m & ((1ull << lane) - 1ull));
    if (kept) idx[goff + wbase + pos] = i;
}

// ---------------------------------------------------------------------------
// Kernel 5: X_pooled[k,:] = X[idx[k],:] * tanh(y[idx[k]]). One wave per row.
// ---------------------------------------------------------------------------
__global__ __launch_bounds__(256) void xpool_kernel(const float* __restrict__ X,
                                                    const double* __restrict__ y,
                                                    const int* __restrict__ idx,
                                                    float* __restrict__ outX) {
    const int wave = threadIdx.x >> 6;
    const int lane = threadIdx.x & 63;
    const int k    = blockIdx.x * 4 + wave;
    const int src  = idx[k];
    const float tf = tanhf((float)y[src]);

    const float4 xv = *reinterpret_cast<const float4*>(X + (size_t)src * F + lane * 4);
    float4 o = {xv.x * tf, xv.y * tf, xv.z * tf, xv.w * tf};
    *reinterpret_cast<float4*>(outX + (size_t)k * F + lane * 4) = o;
}

// ---------------------------------------------------------------------------
// Kernel 6: A_pooled[r,:] = compaction of A[idx[r], kept columns].
// One block per output row: stream the full 16384-col row (float4),
// branchless-compact into a 32 KB LDS buffer (global kept count per row is
// exactly K_KEEP), then store with fully aligned coalesced float4.
// ---------------------------------------------------------------------------
__global__ __launch_bounds__(256) void apool_kernel(const float* __restrict__ A,
                                                    const int* __restrict__ idx,
                                                    const unsigned long long* __restrict__ flagbits,
                                                    const int* __restrict__ wexcl,
                                                    float* __restrict__ outA) {
    __shared__ unsigned long long fb[256];
    __shared__ int we[256];
    __shared__ float buf[K_KEEP + 64];
    const int t   = threadIdx.x;
    const int row = blockIdx.x;
    fb[t] = flagbits[t];
    we[t] = wexcl[t];
    __syncthreads();

    const int ridx = idx[row];
    const float* __restrict__ arow = A + (size_t)ridx * N;
    const int dump = K_KEEP + (t & 63);

    #pragma unroll
    for (int seg = 0; seg < 8; ++seg) {
        const int c0 = seg * 2048 + t * 8;
        const float4 v0 = *reinterpret_cast<const float4*>(arow + c0);
        const float4 v1 = *reinterpret_cast<const float4*>(arow + c0 + 4);
        const int w = c0 >> 6;
        const unsigned long long fw = fb[w];
        const int bit0 = c0 & 63;
        int base = we[w] + __popcll(fw & ((1ull << bit0) - 1ull));
        const unsigned f = (unsigned)((fw >> bit0) & 0xFFull);
        const float vals[8] = {v0.x, v0.y, v0.z, v0.w, v1.x, v1.y, v1.z, v1.w};
        #pragma unroll
        for (int e = 0; e < 8; ++e) {
            const int kp = (f >> e) & 1u;
            buf[kp ? base : dump] = vals[e];
            base += kp;
        }
    }
    __syncthreads();

    float4* __restrict__ ob = reinterpret_cast<float4*>(outA + (size_t)row * K_KEEP);
    const float4* __restrict__ bb = reinterpret_cast<const float4*>(buf);
    #pragma unroll
    for (int s = 0; s < 8; ++s) ob[s * 256 + t] = bb[s * 256 + t];
}

// ---------------------------------------------------------------------------
extern "C" void kernel_launch(void* const* d_in, const int* in_sizes, int n_in,
                              void* d_out, int out_size, void* d_ws, size_t ws_size,
                              hipStream_t stream) {
    const float* X = (const float*)d_in[0];  // [N, F]
    const float* A = (const float*)d_in[1];  // [N, N]
    const float* p = (const float*)d_in[2];  // [F, 1]

    float* out  = (float*)d_out;
    float* outX = out;                          // [K_KEEP, F]
    float* outA = out + (size_t)K_KEEP * F;     // [K_KEEP, K_KEEP]

    char* ws = (char*)d_ws;
    double*             y        = (double*)ws;                          // 131072 B
    unsigned long long* key      = (unsigned long long*)(ws + 131072);   // 131072 B
    unsigned short*     rankp    = (unsigned short*)(ws + 262144);       // 16*N*2 = 524288 B
    int*                idx      = (int*)(ws + 786432);                  // 32768 B
    unsigned long long* flagbits = (unsigned long long*)(ws + 819200);   // 2048 B
    int*                blkcnt   = (int*)(ws + 821248);                  // 256 B
    int*                wexcl    = (int*)(ws + 821504);                  // 1024 B

    score_kernel<<<N / 4, 256, 0, stream>>>(X, p, y, key);
    rank_kernel<<<dim3(16, 16), 256, 0, stream>>>(key, rankp);
    flags_kernel<<<N / 256, 256, 0, stream>>>(rankp, flagbits, blkcnt);
    emit_kernel<<<N / 256, 256, 0, stream>>>(blkcnt, flagbits, idx, wexcl);
    xpool_kernel<<<K_KEEP / 4, 256, 0, stream>>>(X, y, idx, outX);
    apool_kernel<<<K_KEEP, 256, 0, stream>>>(A, idx, flagbits, wexcl, outA);
}

// Round 4
// 197.127 us; speedup vs baseline: 1.6792x; 1.0278x over previous
//
#include <hip/hip_runtime.h>
#include <math.h>

#define N 16384
#define F 256
#define K_KEEP 8192
#define JCH 1024   // j-chunk length for rank kernel
#define QS 4096    // columns per apool block (quarter row)

// ---------------------------------------------------------------------------
// Kernel 1: y[i] = dot(X[i,:], p)/||p|| (fp64 accum) + monotone u64 sort key.
// One wave per row; lane l covers 4 consecutive floats.
// ---------------------------------------------------------------------------
__global__ __launch_bounds__(256) void score_kernel(const float* __restrict__ X,
                                                    const float* __restrict__ p,
                                                    double* __restrict__ y,
                                                    unsigned long long* __restrict__ key) {
    const int wave = threadIdx.x >> 6;
    const int lane = threadIdx.x & 63;
    const int row  = blockIdx.x * 4 + wave;

    const float4 pv = *reinterpret_cast<const float4*>(p + lane * 4);
    const float4 xv = *reinterpret_cast<const float4*>(X + (size_t)row * F + lane * 4);

    double pp = (double)pv.x * pv.x + (double)pv.y * pv.y +
                (double)pv.z * pv.z + (double)pv.w * pv.w;
    double xp = (double)xv.x * pv.x + (double)xv.y * pv.y +
                (double)xv.z * pv.z + (double)xv.w * pv.w;

    #pragma unroll
    for (int off = 32; off >= 1; off >>= 1) {
        pp += __shfl_down(pp, off, 64);
        xp += __shfl_down(xp, off, 64);
    }
    if (lane == 0) {
        const double yy = xp / sqrt(pp);
        y[row] = yy;
        const long long b = __double_as_longlong(yy);
        key[row] = (unsigned long long)b ^
                   ((b < 0) ? 0xFFFFFFFFFFFFFFFFULL : 0x8000000000000000ULL);
    }
}

// ---------------------------------------------------------------------------
// Kernel 2: partial ranks. 2 i per thread amortizes each LDS broadcast read;
// 512 blocks (2/CU) for latency hiding. Keys are distinct doubles, so strict
// u64 > is the exact top_k order (self-compare auto-excluded).
// ---------------------------------------------------------------------------
__global__ __launch_bounds__(256) void rank_kernel(const unsigned long long* __restrict__ key,
                                                   unsigned short* __restrict__ rankp) {
    __shared__ unsigned long long kch[JCH];
    const int jc    = blockIdx.y;
    const int jbase = jc * JCH;
    for (int t = threadIdx.x; t < JCH; t += 256) kch[t] = key[jbase + t];
    __syncthreads();

    const int ibase = blockIdx.x * 512 + threadIdx.x;
    const unsigned long long k0 = key[ibase];
    const unsigned long long k1 = key[ibase + 256];
    int c0 = 0, c1 = 0;
    #pragma unroll 8
    for (int jj = 0; jj < JCH; ++jj) {
        const unsigned long long kj = kch[jj];
        c0 += (int)(kj > k0);
        c1 += (int)(kj > k1);
    }
    rankp[jc * N + ibase      ] = (unsigned short)c0;
    rankp[jc * N + ibase + 256] = (unsigned short)c1;
}

// ---------------------------------------------------------------------------
// Kernel 3: total rank -> kept flags (64-bit words) + per-256-chunk counts.
// ---------------------------------------------------------------------------
__global__ __launch_bounds__(256) void flags_kernel(const unsigned short* __restrict__ rankp,
                                                    unsigned long long* __restrict__ flagbits,
                                                    int* __restrict__ blkcnt) {
    __shared__ int wc[4];
    const int b = blockIdx.x;            // 64 blocks
    const int i = b * 256 + threadIdx.x; // coalesced
    int r = 0;
    #pragma unroll
    for (int jc = 0; jc < 16; ++jc) r += (int)rankp[jc * N + i];
    const bool kept = (r < K_KEEP);
    const unsigned long long m = __ballot(kept);
    const int lane = threadIdx.x & 63;
    const int wave = threadIdx.x >> 6;
    if (lane == 0) { flagbits[i >> 6] = m; wc[wave] = __popcll(m); }
    __syncthreads();
    if (threadIdx.x == 0) blkcnt[b] = wc[0] + wc[1] + wc[2] + wc[3];
}

// ---------------------------------------------------------------------------
// Kernel 4: ordered compaction of kept indices (ascending) + exclusive
// kept-count prefix per 64-column word (wexcl[256], used by apool).
// ---------------------------------------------------------------------------
__global__ __launch_bounds__(256) void emit_kernel(const int* __restrict__ blkcnt,
                                                   const unsigned long long* __restrict__ flagbits,
                                                   int* __restrict__ idx,
                                                   int* __restrict__ wexcl) {
    __shared__ int bc[64];
    __shared__ int woff[4];
    const int t = threadIdx.x;
    const int b = blockIdx.x;            // 64 blocks
    if (t < 64) bc[t] = blkcnt[t];
    __syncthreads();

    int goff = 0;
    for (int j = 0; j < b; ++j) goff += bc[j];   // LDS broadcast reads

    if (t < 4) {
        int s = goff;
        for (int q = 0; q < t; ++q) s += __popcll(flagbits[4 * b + q]);
        wexcl[4 * b + t] = s;
    }

    const int i = b * 256 + t;
    const unsigned long long m = flagbits[i >> 6];
    const int lane = t & 63;
    const int wave = t >> 6;
    const bool kept = (m >> lane) & 1ull;
    if (lane == 0) woff[wave] = __popcll(m);
    __syncthreads();
    int wbase = 0;
    for (int w = 0; w < wave; ++w) wbase += woff[w];
    const int pos = __popcll(m & ((1ull << lane) - 1ull));
    if (kept) idx[goff + wbase + pos] = i;
}

// ---------------------------------------------------------------------------
// Kernel 5: X_pooled[k,:] = X[idx[k],:] * tanh(y[idx[k]]). One wave per row.
// ---------------------------------------------------------------------------
__global__ __launch_bounds__(256) void xpool_kernel(const float* __restrict__ X,
                                                    const double* __restrict__ y,
                                                    const int* __restrict__ idx,
                                                    float* __restrict__ outX) {
    const int wave = threadIdx.x >> 6;
    const int lane = threadIdx.x & 63;
    const int k    = blockIdx.x * 4 + wave;
    const int src  = idx[k];
    const float tf = tanhf((float)y[src]);

    const float4 xv = *reinterpret_cast<const float4*>(X + (size_t)src * F + lane * 4);
    float4 o = {xv.x * tf, xv.y * tf, xv.z * tf, xv.w * tf};
    *reinterpret_cast<float4*>(outX + (size_t)k * F + lane * 4) = o;
}

// ---------------------------------------------------------------------------
// Kernel 6: A_pooled[r, kb:ke] for one (row, quarter). Invert the compaction
// into a gather: stage the 4096-col quarter of A[idx[r],:] linearly in LDS
// (coalesced float4 reads, conflict-free ds_write_b128), then output k in
// [kb,ke) reads buf[idx[k] - qbase] (avg source spacing 2 words -> ~2
// lanes/bank on ds_read_b32 = free) and stores a coalesced dword.
// 16 KB LDS -> 8 blocks/CU.
// ---------------------------------------------------------------------------
__global__ __launch_bounds__(256) void apool_kernel(const float* __restrict__ A,
                                                    const int* __restrict__ idx,
                                                    const int* __restrict__ wexcl,
                                                    float* __restrict__ outA) {
    __shared__ float buf[QS];
    const int t   = threadIdx.x;
    const int row = blockIdx.x >> 2;
    const int h   = blockIdx.x & 3;

    const int ridx = idx[row];                 // uniform scalar load
    const int kb   = wexcl[h * 64];            // uniform
    const int ke   = (h < 3) ? wexcl[h * 64 + 64] : K_KEEP;

    const float4* __restrict__ a4 =
        reinterpret_cast<const float4*>(A + (size_t)ridx * N + h * QS);
    float4* __restrict__ b4 = reinterpret_cast<float4*>(buf);
    #pragma unroll
    for (int s = 0; s < 4; ++s) b4[s * 256 + t] = a4[s * 256 + t];
    __syncthreads();

    float* __restrict__ orow = outA + (size_t)row * K_KEEP;
    const int qbase = h * QS;
    for (int k = kb + t; k < ke; k += 256) {
        const int src = idx[k] - qbase;        // coalesced L2-hot load
        orow[k] = buf[src];
    }
}

// ---------------------------------------------------------------------------
extern "C" void kernel_launch(void* const* d_in, const int* in_sizes, int n_in,
                              void* d_out, int out_size, void* d_ws, size_t ws_size,
                              hipStream_t stream) {
    const float* X = (const float*)d_in[0];  // [N, F]
    const float* A = (const float*)d_in[1];  // [N, N]
    const float* p = (const float*)d_in[2];  // [F, 1]

    float* out  = (float*)d_out;
    float* outX = out;                          // [K_KEEP, F]
    float* outA = out + (size_t)K_KEEP * F;     // [K_KEEP, K_KEEP]

    char* ws = (char*)d_ws;
    double*             y        = (double*)ws;                          // 131072 B
    unsigned long long* key      = (unsigned long long*)(ws + 131072);   // 131072 B
    unsigned short*     rankp    = (unsigned short*)(ws + 262144);       // 16*N*2 = 524288 B
    int*                idx      = (int*)(ws + 786432);                  // 32768 B
    unsigned long long* flagbits = (unsigned long long*)(ws + 819200);   // 2048 B
    int*                blkcnt   = (int*)(ws + 821248);                  // 256 B
    int*                wexcl    = (int*)(ws + 821504);                  // 1024 B

    score_kernel<<<N / 4, 256, 0, stream>>>(X, p, y, key);
    rank_kernel<<<dim3(32, 16), 256, 0, stream>>>(key, rankp);
    flags_kernel<<<N / 256, 256, 0, stream>>>(rankp, flagbits, blkcnt);
    emit_kernel<<<N / 256, 256, 0, stream>>>(blkcnt, flagbits, idx, wexcl);
    xpool_kernel<<<K_KEEP / 4, 256, 0, stream>>>(X, y, idx, outX);
    apool_kernel<<<K_KEEP * 4, 256, 0, stream>>>(A, idx, wexcl, outA);
}

// Round 6
// 178.632 us; speedup vs baseline: 1.8530x; 1.1035x over previous
//
#include <hip/hip_runtime.h>
#include <math.h>

#define N 16384
#define F 256
#define K_KEEP 8192
#define JCH 512    // j-chunk length for rank kernel
#define IPT 4      // i per thread in rank kernel
#define QS 4096    // columns per apool block (quarter row)
#define APOOL_BLOCKS (K_KEEP * 4)

typedef float f32x4 __attribute__((ext_vector_type(4)));  // native vec for nontemporal builtins

// ---------------------------------------------------------------------------
// Kernel 1: y[i] = dot(X[i,:], p)/||p|| (fp64 accum) + monotone u64 sort key.
// One wave per row; lane l covers 4 consecutive floats.
// ---------------------------------------------------------------------------
__global__ __launch_bounds__(256) void score_kernel(const float* __restrict__ X,
                                                    const float* __restrict__ p,
                                                    double* __restrict__ y,
                                                    unsigned long long* __restrict__ key) {
    const int wave = threadIdx.x >> 6;
    const int lane = threadIdx.x & 63;
    const int row  = blockIdx.x * 4 + wave;

    const float4 pv = *reinterpret_cast<const float4*>(p + lane * 4);
    const float4 xv = *reinterpret_cast<const float4*>(X + (size_t)row * F + lane * 4);

    double pp = (double)pv.x * pv.x + (double)pv.y * pv.y +
                (double)pv.z * pv.z + (double)pv.w * pv.w;
    double xp = (double)xv.x * pv.x + (double)xv.y * pv.y +
                (double)xv.z * pv.z + (double)xv.w * pv.w;

    #pragma unroll
    for (int off = 32; off >= 1; off >>= 1) {
        pp += __shfl_down(pp, off, 64);
        xp += __shfl_down(xp, off, 64);
    }
    if (lane == 0) {
        const double yy = xp / sqrt(pp);
        y[row] = yy;
        const long long b = __double_as_longlong(yy);
        key[row] = (unsigned long long)b ^
                   ((b < 0) ? 0xFFFFFFFFFFFFFFFFULL : 0x8000000000000000ULL);
    }
}

// ---------------------------------------------------------------------------
// Kernel 2: partial ranks. IPT=4 i-values per thread amortize each LDS read
// over 4 compares; b128 reads fetch 2 keys per LDS instruction. Keys are
// distinct doubles, so strict u64 > is the exact top_k order.
// ---------------------------------------------------------------------------
__global__ __launch_bounds__(256) void rank_kernel(const unsigned long long* __restrict__ key,
                                                   unsigned short* __restrict__ rankp) {
    __shared__ ulonglong2 kch2[JCH / 2];   // 4 KB
    const int t     = threadIdx.x;
    const int jc    = blockIdx.y;
    const int jbase = jc * JCH;
    kch2[t] = *reinterpret_cast<const ulonglong2*>(key + jbase + 2 * t);
    __syncthreads();

    const int ibase = blockIdx.x * (256 * IPT) + t;
    const unsigned long long k0 = key[ibase];
    const unsigned long long k1 = key[ibase + 256];
    const unsigned long long k2 = key[ibase + 512];
    const unsigned long long k3 = key[ibase + 768];
    int c0 = 0, c1 = 0, c2 = 0, c3 = 0;
    #pragma unroll 8
    for (int jj = 0; jj < JCH / 2; ++jj) {
        const ulonglong2 kk = kch2[jj];
        c0 += (int)(kk.x > k0) + (int)(kk.y > k0);
        c1 += (int)(kk.x > k1) + (int)(kk.y > k1);
        c2 += (int)(kk.x > k2) + (int)(kk.y > k2);
        c3 += (int)(kk.x > k3) + (int)(kk.y > k3);
    }
    rankp[jc * N + ibase      ] = (unsigned short)c0;
    rankp[jc * N + ibase + 256] = (unsigned short)c1;
    rankp[jc * N + ibase + 512] = (unsigned short)c2;
    rankp[jc * N + ibase + 768] = (unsigned short)c3;
}

// ---------------------------------------------------------------------------
// Kernel 3: total rank -> kept flags (64-bit words).
// ---------------------------------------------------------------------------
__global__ __launch_bounds__(256) void flags_kernel(const unsigned short* __restrict__ rankp,
                                                    unsigned long long* __restrict__ flagbits) {
    const int i = blockIdx.x * 256 + threadIdx.x; // coalesced
    int r = 0;
    #pragma unroll
    for (int jc = 0; jc < N / JCH; ++jc) r += (int)rankp[jc * N + i];
    const bool kept = (r < K_KEEP);
    const unsigned long long m = __ballot(kept);
    if ((threadIdx.x & 63) == 0) flagbits[i >> 6] = m;
}

// ---------------------------------------------------------------------------
// Kernel 4 (single block): popcount+scan the 256 flag words -> wexcl[256];
// emit ascending kept indices idx[] and in-quarter u16 source offsets srcq[].
// ---------------------------------------------------------------------------
__global__ __launch_bounds__(256) void emit_kernel(const unsigned long long* __restrict__ flagbits,
                                                   int* __restrict__ idx,
                                                   unsigned short* __restrict__ srcq,
                                                   int* __restrict__ wexcl) {
    __shared__ int sc[256];
    const int t = threadIdx.x;
    const unsigned long long m = flagbits[t];
    const int c = __popcll(m);
    sc[t] = c;
    __syncthreads();
    for (int off = 1; off < 256; off <<= 1) {
        const int v = (t >= off) ? sc[t - off] : 0;
        __syncthreads();
        sc[t] += v;
        __syncthreads();
    }
    const int excl = sc[t] - c;
    wexcl[t] = excl;

    int base = excl;
    unsigned long long mm = m;
    const int col = t * 64;
    while (mm) {
        const int b = __ffsll((long long)mm) - 1;
        mm &= (mm - 1);
        const int i = col + b;
        idx[base]  = i;
        srcq[base] = (unsigned short)(i & (QS - 1));
        ++base;
    }
}

// ---------------------------------------------------------------------------
// Kernel 5 (fused pool): blocks [0, 32768): A_pooled via LDS-staged quarter
// row + srcq gather + aligned float4 nontemporal stores. Blocks [32768, +2048):
// X_pooled (one wave per kept row).
// ---------------------------------------------------------------------------
__global__ __launch_bounds__(256) void pool_kernel(const float* __restrict__ A,
                                                   const float* __restrict__ X,
                                                   const double* __restrict__ y,
                                                   const int* __restrict__ idx,
                                                   const unsigned short* __restrict__ srcq,
                                                   const int* __restrict__ wexcl,
                                                   float* __restrict__ outX,
                                                   float* __restrict__ outA) {
    const int t = threadIdx.x;

    if (blockIdx.x >= APOOL_BLOCKS) {  // ---- xpool part ----
        const int k    = (blockIdx.x - APOOL_BLOCKS) * 4 + (t >> 6);
        const int lane = t & 63;
        const int src  = idx[k];
        const float tf = tanhf((float)y[src]);
        const float4 xv = *reinterpret_cast<const float4*>(X + (size_t)src * F + lane * 4);
        float4 o = {xv.x * tf, xv.y * tf, xv.z * tf, xv.w * tf};
        *reinterpret_cast<float4*>(outX + (size_t)k * F + lane * 4) = o;
        return;
    }

    // ---- apool part: one (row, quarter) per block ----
    __shared__ float buf[QS];
    const int row  = blockIdx.x >> 2;
    const int h    = blockIdx.x & 3;
    const int ridx = idx[row];                    // uniform
    const int kb   = wexcl[h * 64];               // uniform
    const int ke   = (h < 3) ? wexcl[h * 64 + 64] : K_KEEP;

    const f32x4* __restrict__ a4 =
        reinterpret_cast<const f32x4*>(A + (size_t)ridx * N + h * QS);
    f32x4* __restrict__ b4 = reinterpret_cast<f32x4*>(buf);
    #pragma unroll
    for (int s = 0; s < 4; ++s) b4[s * 256 + t] = __builtin_nontemporal_load(a4 + s * 256 + t);
    __syncthreads();

    float* __restrict__ orow = outA + (size_t)row * K_KEEP;
    const int k4b = (kb + 3) & ~3;
    const int k4e = ke & ~3;
    if (t < (k4b - kb)) orow[kb + t] = buf[srcq[kb + t]];
    if (t < (ke - k4e)) orow[k4e + t] = buf[srcq[k4e + t]];
    for (int k4 = k4b + 4 * t; k4 < k4e; k4 += 1024) {
        const ushort4 s4 = *reinterpret_cast<const ushort4*>(srcq + k4);
        f32x4 v = {buf[s4.x], buf[s4.y], buf[s4.z], buf[s4.w]};
        __builtin_nontemporal_store(v, reinterpret_cast<f32x4*>(orow + k4));
    }
}

// ---------------------------------------------------------------------------
extern "C" void kernel_launch(void* const* d_in, const int* in_sizes, int n_in,
                              void* d_out, int out_size, void* d_ws, size_t ws_size,
                              hipStream_t stream) {
    const float* X = (const float*)d_in[0];  // [N, F]
    const float* A = (const float*)d_in[1];  // [N, N]
    const float* p = (const float*)d_in[2];  // [F, 1]

    float* out  = (float*)d_out;
    float* outX = out;                          // [K_KEEP, F]
    float* outA = out + (size_t)K_KEEP * F;     // [K_KEEP, K_KEEP]

    char* ws = (char*)d_ws;
    double*             y        = (double*)ws;                           // 131072 B
    unsigned long long* key      = (unsigned long long*)(ws + 131072);    // 131072 B
    unsigned short*     rankp    = (unsigned short*)(ws + 262144);        // 32*N*2 = 1048576 B
    unsigned long long* flagbits = (unsigned long long*)(ws + 1310720);   // 2048 B
    int*                wexcl    = (int*)(ws + 1312768);                  // 1024 B
    int*                idx      = (int*)(ws + 1313792);                  // 32768 B
    unsigned short*     srcq     = (unsigned short*)(ws + 1346560);       // 16384 B

    score_kernel<<<N / 4, 256, 0, stream>>>(X, p, y, key);
    rank_kernel<<<dim3(N / (256 * IPT), N / JCH), 256, 0, stream>>>(key, rankp);
    flags_kernel<<<N / 256, 256, 0, stream>>>(rankp, flagbits);
    emit_kernel<<<1, 256, 0, stream>>>(flagbits, idx, srcq, wexcl);
    pool_kernel<<<APOOL_BLOCKS + K_KEEP / 4, 256, 0, stream>>>(A, X, y, idx, srcq, wexcl,
                                                               outX, outA);
}